// Round 10
// baseline (367.201 us; speedup 1.0000x reference)
//
#include <hip/hip_runtime.h>
#include <math.h>

#define CDIV(a,b) (((a)+(b)-1)/(b))

// ---------- deg[dst]++ (int histogram) ----------
__global__ __launch_bounds__(256) void deg_kernel(
    const int* __restrict__ dst, int E, int* __restrict__ deg)
{
    int e = blockIdx.x * 256 + threadIdx.x;
    if (e >= E) return;
    atomicAdd(&deg[dst[e]], 1);
}

__global__ __launch_bounds__(256) void dinv_kernel(
    const int* __restrict__ deg, float* __restrict__ dinv, int N)
{
    int i = blockIdx.x * 256 + threadIdx.x;
    if (i >= N) return;
    dinv[i] = 1.0f / sqrtf((float)deg[i] + 1.0f);  // +1 for self-loop
}

// ---------- hierarchical exclusive scan ----------
__global__ __launch_bounds__(1024) void block_scan_kernel(
    const int* __restrict__ deg, int* __restrict__ excl,
    int* __restrict__ bsums, int N)
{
    __shared__ int buf[1024];
    const int t = threadIdx.x;
    const int i = blockIdx.x * 1024 + t;
    int v = (i < N) ? deg[i] : 0;
    buf[t] = v;
    __syncthreads();
    for (int offs = 1; offs < 1024; offs <<= 1) {
        int add = (t >= offs) ? buf[t - offs] : 0;
        __syncthreads();
        buf[t] += add;
        __syncthreads();
    }
    if (i < N) excl[i] = buf[t] - v;
    if (t == 1023) bsums[blockIdx.x] = buf[t];
}

__global__ __launch_bounds__(1024) void scan_bsums_kernel(
    int* __restrict__ bsums, int nb)
{
    __shared__ int buf[1024];
    const int t = threadIdx.x;
    int v = (t < nb) ? bsums[t] : 0;
    buf[t] = v;
    __syncthreads();
    for (int offs = 1; offs < 1024; offs <<= 1) {
        int add = (t >= offs) ? buf[t - offs] : 0;
        __syncthreads();
        buf[t] += add;
        __syncthreads();
    }
    if (t < nb) bsums[t] = buf[t] - v;  // exclusive
}

__global__ __launch_bounds__(256) void add_offsets_kernel(
    int* __restrict__ rowptr, int* __restrict__ cursor,
    const int* __restrict__ bsums, int N, int E)
{
    int i = blockIdx.x * 256 + threadIdx.x;
    if (i < N) {
        int v = rowptr[i] + bsums[i >> 10];
        rowptr[i] = v;
        cursor[i] = v;
    }
    if (i == N) rowptr[N] = E;
}

// ---------- scatter edges into CSR slots ----------
__global__ __launch_bounds__(256) void csr_build_kernel(
    const int* __restrict__ src, const int* __restrict__ dst,
    int* __restrict__ cursor, int* __restrict__ csr_src, int E)
{
    int e = blockIdx.x * 256 + threadIdx.x;
    if (e >= E) return;
    int pos = atomicAdd(&cursor[dst[e]], 1);
    csr_src[pos] = src[e];
}

// ---------- GEMM: tmp = A@W ----------
// W (col-slice) staged in LDS once, single barrier, barrier-free k-loop.
// CHUNK16: store tmp in chunked layout [FO/16][N][16] for XCD-resident agg.
template<int FI, int FO, int COLS, int ROWS, bool CHUNK16>
__global__ __launch_bounds__(256, 4) void gemm_kernel(
    const float* __restrict__ A, const float* __restrict__ W,
    float* __restrict__ tmp, int N)
{
    constexpr int NCB = FO / COLS;    // col-blocks
    constexpr int CT  = COLS / 4;     // col-threads (float4 each)
    constexpr int RT  = 256 / CT;     // row-threads
    constexpr int RPT = ROWS / RT;    // rows per thread

    __shared__ float sW[FI][COLS];

    const int t    = threadIdx.x;
    const int colb = (NCB > 1) ? (blockIdx.x % NCB) : 0;
    const int rowb = (NCB > 1) ? (blockIdx.x / NCB) : blockIdx.x;

    #pragma unroll
    for (int it = 0; it < (FI * COLS / 4) / 256; ++it) {
        int idx = it * 256 + t;
        int k   = idx / CT;
        int cq  = idx % CT;
        *reinterpret_cast<float4*>(&sW[k][cq * 4]) =
            *reinterpret_cast<const float4*>(W + (size_t)k * FO + colb * COLS + cq * 4);
    }
    __syncthreads();

    const int c0 = (t % CT) * 4;
    const int r0 = t / CT;

    const float* aptr[RPT];
    #pragma unroll
    for (int rr = 0; rr < RPT; ++rr) {
        int row = rowb * ROWS + r0 + rr * RT;
        int rc  = (row < N) ? row : (N - 1);   // clamp loads, guard stores
        aptr[rr] = A + (size_t)rc * FI;
    }

    float acc[RPT][4];
    #pragma unroll
    for (int rr = 0; rr < RPT; ++rr)
        #pragma unroll
        for (int c = 0; c < 4; ++c) acc[rr][c] = 0.0f;

    #pragma unroll 8
    for (int k4 = 0; k4 < FI / 4; ++k4) {
        float4 w0 = *reinterpret_cast<const float4*>(&sW[k4 * 4 + 0][c0]);
        float4 w1 = *reinterpret_cast<const float4*>(&sW[k4 * 4 + 1][c0]);
        float4 w2 = *reinterpret_cast<const float4*>(&sW[k4 * 4 + 2][c0]);
        float4 w3 = *reinterpret_cast<const float4*>(&sW[k4 * 4 + 3][c0]);
        #pragma unroll
        for (int rr = 0; rr < RPT; ++rr) {
            float4 a = *reinterpret_cast<const float4*>(aptr[rr] + k4 * 4);
            acc[rr][0] += a.x * w0.x + a.y * w1.x + a.z * w2.x + a.w * w3.x;
            acc[rr][1] += a.x * w0.y + a.y * w1.y + a.z * w2.y + a.w * w3.y;
            acc[rr][2] += a.x * w0.z + a.y * w1.z + a.z * w2.z + a.w * w3.z;
            acc[rr][3] += a.x * w0.w + a.y * w1.w + a.z * w2.w + a.w * w3.w;
        }
    }

    const int gc0 = colb * COLS + c0;
    #pragma unroll
    for (int rr = 0; rr < RPT; ++rr) {
        int row = rowb * ROWS + r0 + rr * RT;
        if (row >= N) continue;
        float4 v = make_float4(acc[rr][0], acc[rr][1], acc[rr][2], acc[rr][3]);
        if (CHUNK16) {
            *reinterpret_cast<float4*>(tmp + (size_t)(gc0 >> 4) * N * 16
                                           + (size_t)row * 16 + (gc0 & 15)) = v;
        } else {
            *reinterpret_cast<float4*>(tmp + (size_t)row * FO + gc0) = v;
        }
    }
}

// ---------- chunked gather agg, node-slot parallel, U=4 MLP ----------
// tmp layout [NC][N][16]; chunk = bid % NC rides XCD round-robin -> per-XCD
// L2-resident chunk. Wave = 16 node-slots x 4 lanes. Each slot walks its own
// node's edges 4-at-a-time (4 independent accumulator chains). csr_src read
// nontemporally so the streaming index walk doesn't evict the chunk from L2.
template<int FOFULL, int NC>
__global__ __launch_bounds__(256) void agg_chunk_kernel(
    const int* __restrict__ rowptr, const int* __restrict__ csr_src,
    const float* __restrict__ dinv, const float* __restrict__ tmp,
    const float* __restrict__ b, float* __restrict__ h, int N)
{
    const int bid   = blockIdx.x;
    const int chunk = bid % NC;
    const int lane  = threadIdx.x & 63;
    const int slot  = lane >> 2;     // 0..15
    const int f     = lane & 3;      // float4 index within 16-col chunk
    const int node  = (bid / NC) * 64 + (threadIdx.x >> 6) * 16 + slot;
    if (node >= N) return;

    const float* tc = tmp + (size_t)chunk * N * 16;
    const float dvd = dinv[node];
    const int jb = rowptr[node], je = rowptr[node + 1];

    float4 a0 = make_float4(0.f, 0.f, 0.f, 0.f);
    float4 a1 = make_float4(0.f, 0.f, 0.f, 0.f);
    float4 a2 = make_float4(0.f, 0.f, 0.f, 0.f);
    float4 a3 = make_float4(0.f, 0.f, 0.f, 0.f);
    int j = jb;
    for (; j + 4 <= je; j += 4) {
        int s0 = __builtin_nontemporal_load(&csr_src[j + 0]);
        int s1 = __builtin_nontemporal_load(&csr_src[j + 1]);
        int s2 = __builtin_nontemporal_load(&csr_src[j + 2]);
        int s3 = __builtin_nontemporal_load(&csr_src[j + 3]);
        float w0 = dinv[s0] * dvd;
        float w1 = dinv[s1] * dvd;
        float w2 = dinv[s2] * dvd;
        float w3 = dinv[s3] * dvd;
        float4 v0 = *reinterpret_cast<const float4*>(tc + (size_t)s0 * 16 + f * 4);
        float4 v1 = *reinterpret_cast<const float4*>(tc + (size_t)s1 * 16 + f * 4);
        float4 v2 = *reinterpret_cast<const float4*>(tc + (size_t)s2 * 16 + f * 4);
        float4 v3 = *reinterpret_cast<const float4*>(tc + (size_t)s3 * 16 + f * 4);
        a0.x += v0.x * w0; a0.y += v0.y * w0; a0.z += v0.z * w0; a0.w += v0.w * w0;
        a1.x += v1.x * w1; a1.y += v1.y * w1; a1.z += v1.z * w1; a1.w += v1.w * w1;
        a2.x += v2.x * w2; a2.y += v2.y * w2; a2.z += v2.z * w2; a2.w += v2.w * w2;
        a3.x += v3.x * w3; a3.y += v3.y * w3; a3.z += v3.z * w3; a3.w += v3.w * w3;
    }
    for (; j < je; ++j) {
        int s = __builtin_nontemporal_load(&csr_src[j]);
        float w = dinv[s] * dvd;
        float4 v = *reinterpret_cast<const float4*>(tc + (size_t)s * 16 + f * 4);
        a0.x += v.x * w; a0.y += v.y * w; a0.z += v.z * w; a0.w += v.w * w;
    }
    const float d2 = dvd * dvd;
    float4 sv = *reinterpret_cast<const float4*>(tc + (size_t)node * 16 + f * 4);
    const float4 bb = *reinterpret_cast<const float4*>(b + chunk * 16 + f * 4);
    float4 a;
    a.x = fmaxf((a0.x + a1.x) + (a2.x + a3.x) + sv.x * d2 + bb.x, 0.f);
    a.y = fmaxf((a0.y + a1.y) + (a2.y + a3.y) + sv.y * d2 + bb.y, 0.f);
    a.z = fmaxf((a0.z + a1.z) + (a2.z + a3.z) + sv.z * d2 + bb.z, 0.f);
    a.w = fmaxf((a0.w + a1.w) + (a2.w + a3.w) + sv.w * d2 + bb.w, 0.f);
    *reinterpret_cast<float4*>(h + (size_t)node * FOFULL + chunk * 16 + f * 4) = a;
}

// ---------- last layer: node-slot agg + fused final linear (FO=32) ----------
// Wave = 8 node-slots x 8 lanes (float4 each), U=4 chains per slot.
__global__ __launch_bounds__(256) void agg_final_kernel(
    const int* __restrict__ rowptr, const int* __restrict__ csr_src,
    const float* __restrict__ dinv, const float* __restrict__ tmp,
    const float* __restrict__ b,
    const float* __restrict__ Wl, const float* __restrict__ bl,
    float* __restrict__ out, int N)
{
    constexpr int FO = 32;
    const int lane = threadIdx.x & 63;
    const int slot = lane >> 3;      // 0..7
    const int f    = lane & 7;       // float4 index within 32-col row
    const int node = blockIdx.x * 32 + (threadIdx.x >> 6) * 8 + slot;
    if (node >= N) return;

    const float dvd = dinv[node];
    const int jb = rowptr[node], je = rowptr[node + 1];

    float4 a0 = make_float4(0.f, 0.f, 0.f, 0.f);
    float4 a1 = make_float4(0.f, 0.f, 0.f, 0.f);
    float4 a2 = make_float4(0.f, 0.f, 0.f, 0.f);
    float4 a3 = make_float4(0.f, 0.f, 0.f, 0.f);
    int j = jb;
    for (; j + 4 <= je; j += 4) {
        int s0 = __builtin_nontemporal_load(&csr_src[j + 0]);
        int s1 = __builtin_nontemporal_load(&csr_src[j + 1]);
        int s2 = __builtin_nontemporal_load(&csr_src[j + 2]);
        int s3 = __builtin_nontemporal_load(&csr_src[j + 3]);
        float w0 = dinv[s0] * dvd;
        float w1 = dinv[s1] * dvd;
        float w2 = dinv[s2] * dvd;
        float w3 = dinv[s3] * dvd;
        float4 v0 = *reinterpret_cast<const float4*>(tmp + (size_t)s0 * FO + f * 4);
        float4 v1 = *reinterpret_cast<const float4*>(tmp + (size_t)s1 * FO + f * 4);
        float4 v2 = *reinterpret_cast<const float4*>(tmp + (size_t)s2 * FO + f * 4);
        float4 v3 = *reinterpret_cast<const float4*>(tmp + (size_t)s3 * FO + f * 4);
        a0.x += v0.x * w0; a0.y += v0.y * w0; a0.z += v0.z * w0; a0.w += v0.w * w0;
        a1.x += v1.x * w1; a1.y += v1.y * w1; a1.z += v1.z * w1; a1.w += v1.w * w1;
        a2.x += v2.x * w2; a2.y += v2.y * w2; a2.z += v2.z * w2; a2.w += v2.w * w2;
        a3.x += v3.x * w3; a3.y += v3.y * w3; a3.z += v3.z * w3; a3.w += v3.w * w3;
    }
    for (; j < je; ++j) {
        int s = __builtin_nontemporal_load(&csr_src[j]);
        float w = dinv[s] * dvd;
        float4 v = *reinterpret_cast<const float4*>(tmp + (size_t)s * FO + f * 4);
        a0.x += v.x * w; a0.y += v.y * w; a0.z += v.z * w; a0.w += v.w * w;
    }
    const float d2 = dvd * dvd;
    float4 sv = *reinterpret_cast<const float4*>(tmp + (size_t)node * FO + f * 4);
    const float4 bb = *reinterpret_cast<const float4*>(b + f * 4);
    float4 a;
    a.x = fmaxf((a0.x + a1.x) + (a2.x + a3.x) + sv.x * d2 + bb.x, 0.f);
    a.y = fmaxf((a0.y + a1.y) + (a2.y + a3.y) + sv.y * d2 + bb.y, 0.f);
    a.z = fmaxf((a0.z + a1.z) + (a2.z + a3.z) + sv.z * d2 + bb.z, 0.f);
    a.w = fmaxf((a0.w + a1.w) + (a2.w + a3.w) + sv.w * d2 + bb.w, 0.f);

    const float4 wl = *reinterpret_cast<const float4*>(Wl + f * 4);
    float r = a.x * wl.x + a.y * wl.y + a.z * wl.z + a.w * wl.w;
    r += __shfl_xor(r, 1, 64);
    r += __shfl_xor(r, 2, 64);
    r += __shfl_xor(r, 4, 64);
    if (f == 0) out[node] = r + bl[0];
}

extern "C" void kernel_launch(void* const* d_in, const int* in_sizes, int n_in,
                              void* d_out, int out_size, void* d_ws, size_t ws_size,
                              hipStream_t stream)
{
    const float* x  = (const float*)d_in[0];
    const int*   ei = (const int*)d_in[1];   // int inputs arrive as int32
    const float* W1 = (const float*)d_in[2];
    const float* b1 = (const float*)d_in[3];
    const float* W2 = (const float*)d_in[4];
    const float* b2 = (const float*)d_in[5];
    const float* W3 = (const float*)d_in[6];
    const float* b3 = (const float*)d_in[7];
    const float* Wl = (const float*)d_in[8];
    const float* bl = (const float*)d_in[9];
    float* out = (float*)d_out;

    const int N = in_sizes[0] / 128;
    const int E = in_sizes[1] / 2;

    const int* src = ei;        // edge_index row 0
    const int* dst = ei + E;    // edge_index row 1

    char* ws = (char*)d_ws;
    size_t off = 0;
    auto wsalloc = [&](size_t bytes) -> void* {
        void* p = ws + off;
        off = (off + bytes + 255) & ~(size_t)255;
        return p;
    };
    const int NB = CDIV(N, 1024);
    int*   deg     = (int*)  wsalloc((size_t)N * 4);
    float* dinv    = (float*)wsalloc((size_t)N * 4);
    int*   rowptr  = (int*)  wsalloc((size_t)(N + 1) * 4);
    int*   cursor  = (int*)  wsalloc((size_t)N * 4);
    int*   bsums   = (int*)  wsalloc((size_t)NB * 4);
    int*   csr_src = (int*)  wsalloc((size_t)E * 4);
    float* B1      = (float*)wsalloc((size_t)N * 128 * 4);  // tmp (chunked)
    float* B2      = (float*)wsalloc((size_t)N * 128 * 4);  // h
    // total ws use: ~55 MB

    // ---- CSR build ----
    hipMemsetAsync(deg, 0, (size_t)N * 4, stream);
    deg_kernel<<<CDIV(E, 256), 256, 0, stream>>>(dst, E, deg);
    dinv_kernel<<<CDIV(N, 256), 256, 0, stream>>>(deg, dinv, N);
    block_scan_kernel<<<NB, 1024, 0, stream>>>(deg, rowptr, bsums, N);
    scan_bsums_kernel<<<1, 1024, 0, stream>>>(bsums, NB);
    add_offsets_kernel<<<CDIV(N + 1, 256), 256, 0, stream>>>(rowptr, cursor, bsums, N, E);
    csr_build_kernel<<<CDIV(E, 256), 256, 0, stream>>>(src, dst, cursor, csr_src, E);

    // ---- layer 1: 128 -> 128 (chunked tmp, NC=8, 1 chunk per XCD) ----
    gemm_kernel<128, 128, 64, 64, true><<<2 * CDIV(N, 64), 256, 0, stream>>>(x, W1, B1, N);
    agg_chunk_kernel<128, 8><<<8 * CDIV(N, 64), 256, 0, stream>>>(
        rowptr, csr_src, dinv, B1, b1, B2, N);

    // ---- layer 2: 128 -> 64 (chunked tmp, NC=4) ----
    gemm_kernel<128, 64, 64, 64, true><<<CDIV(N, 64), 256, 0, stream>>>(B2, W2, B1, N);
    agg_chunk_kernel<64, 4><<<4 * CDIV(N, 64), 256, 0, stream>>>(
        rowptr, csr_src, dinv, B1, b2, B2, N);

    // ---- layer 3: 64 -> 32, final linear fused (unchunked) ----
    gemm_kernel<64, 32, 32, 64, false><<<CDIV(N, 64), 256, 0, stream>>>(B2, W3, B1, N);
    agg_final_kernel<<<CDIV(N, 32), 256, 0, stream>>>(
        rowptr, csr_src, dinv, B1, b3, Wl, bl, out, N);
}

// Round 11
// 281.677 us; speedup vs baseline: 1.3036x; 1.3036x over previous
//
#include <hip/hip_runtime.h>
#include <math.h>

#define CDIV(a,b) (((a)+(b)-1)/(b))

// ---------- deg[dst]++ (int histogram) ----------
__global__ __launch_bounds__(256) void deg_kernel(
    const int* __restrict__ dst, int E, int* __restrict__ deg)
{
    int e = blockIdx.x * 256 + threadIdx.x;
    if (e >= E) return;
    atomicAdd(&deg[dst[e]], 1);
}

// ---------- hierarchical exclusive scan (pass 1 also emits dinv) ----------
__global__ __launch_bounds__(1024) void block_scan_kernel(
    const int* __restrict__ deg, int* __restrict__ excl,
    int* __restrict__ bsums, float* __restrict__ dinv, int N)
{
    __shared__ int buf[1024];
    const int t = threadIdx.x;
    const int i = blockIdx.x * 1024 + t;
    int v = (i < N) ? deg[i] : 0;
    buf[t] = v;
    __syncthreads();
    for (int offs = 1; offs < 1024; offs <<= 1) {
        int add = (t >= offs) ? buf[t - offs] : 0;
        __syncthreads();
        buf[t] += add;
        __syncthreads();
    }
    if (i < N) {
        excl[i] = buf[t] - v;
        dinv[i] = 1.0f / sqrtf((float)v + 1.0f);  // +1 self-loop
    }
    if (t == 1023) bsums[blockIdx.x] = buf[t];
}

__global__ __launch_bounds__(1024) void scan_bsums_kernel(
    int* __restrict__ bsums, int nb)
{
    __shared__ int buf[1024];
    const int t = threadIdx.x;
    int v = (t < nb) ? bsums[t] : 0;
    buf[t] = v;
    __syncthreads();
    for (int offs = 1; offs < 1024; offs <<= 1) {
        int add = (t >= offs) ? buf[t - offs] : 0;
        __syncthreads();
        buf[t] += add;
        __syncthreads();
    }
    if (t < nb) bsums[t] = buf[t] - v;  // exclusive
}

__global__ __launch_bounds__(256) void add_offsets_kernel(
    int* __restrict__ rowptr, int* __restrict__ cursor,
    const int* __restrict__ bsums, int N, int E)
{
    int i = blockIdx.x * 256 + threadIdx.x;
    if (i < N) {
        int v = rowptr[i] + bsums[i >> 10];
        rowptr[i] = v;
        cursor[i] = v;
    }
    if (i == N) rowptr[N] = E;
}

// ---------- scatter edges into CSR slots ----------
__global__ __launch_bounds__(256) void csr_build_kernel(
    const int* __restrict__ src, const int* __restrict__ dst,
    int* __restrict__ cursor, int* __restrict__ csr_src, int E)
{
    int e = blockIdx.x * 256 + threadIdx.x;
    if (e >= E) return;
    int pos = atomicAdd(&cursor[dst[e]], 1);
    csr_src[pos] = src[e];
}

// ---------- GEMM: tmp = A@W ----------
// W (col-slice) staged in LDS once, single barrier, barrier-free k-loop.
// A read from global: CT lanes of a row-group hit the same float4 (broadcast).
template<int FI, int FO, int COLS, int ROWS>
__global__ __launch_bounds__(256, 4) void gemm_kernel(
    const float* __restrict__ A, const float* __restrict__ W,
    float* __restrict__ tmp, int N)
{
    constexpr int NCB = FO / COLS;    // col-blocks
    constexpr int CT  = COLS / 4;     // col-threads (float4 each)
    constexpr int RT  = 256 / CT;     // row-threads
    constexpr int RPT = ROWS / RT;    // rows per thread

    __shared__ float sW[FI][COLS];

    const int t    = threadIdx.x;
    const int colb = (NCB > 1) ? (blockIdx.x % NCB) : 0;
    const int rowb = (NCB > 1) ? (blockIdx.x / NCB) : blockIdx.x;

    #pragma unroll
    for (int it = 0; it < (FI * COLS / 4) / 256; ++it) {
        int idx = it * 256 + t;
        int k   = idx / CT;
        int cq  = idx % CT;
        *reinterpret_cast<float4*>(&sW[k][cq * 4]) =
            *reinterpret_cast<const float4*>(W + (size_t)k * FO + colb * COLS + cq * 4);
    }
    __syncthreads();

    const int c0 = (t % CT) * 4;
    const int r0 = t / CT;

    const float* aptr[RPT];
    #pragma unroll
    for (int rr = 0; rr < RPT; ++rr) {
        int row = rowb * ROWS + r0 + rr * RT;
        int rc  = (row < N) ? row : (N - 1);   // clamp loads, guard stores
        aptr[rr] = A + (size_t)rc * FI;
    }

    float acc[RPT][4];
    #pragma unroll
    for (int rr = 0; rr < RPT; ++rr)
        #pragma unroll
        for (int c = 0; c < 4; ++c) acc[rr][c] = 0.0f;

    #pragma unroll 8
    for (int k4 = 0; k4 < FI / 4; ++k4) {
        float4 w0 = *reinterpret_cast<const float4*>(&sW[k4 * 4 + 0][c0]);
        float4 w1 = *reinterpret_cast<const float4*>(&sW[k4 * 4 + 1][c0]);
        float4 w2 = *reinterpret_cast<const float4*>(&sW[k4 * 4 + 2][c0]);
        float4 w3 = *reinterpret_cast<const float4*>(&sW[k4 * 4 + 3][c0]);
        #pragma unroll
        for (int rr = 0; rr < RPT; ++rr) {
            float4 a = *reinterpret_cast<const float4*>(aptr[rr] + k4 * 4);
            acc[rr][0] += a.x * w0.x + a.y * w1.x + a.z * w2.x + a.w * w3.x;
            acc[rr][1] += a.x * w0.y + a.y * w1.y + a.z * w2.y + a.w * w3.y;
            acc[rr][2] += a.x * w0.z + a.y * w1.z + a.z * w2.z + a.w * w3.z;
            acc[rr][3] += a.x * w0.w + a.y * w1.w + a.z * w2.w + a.w * w3.w;
        }
    }

    #pragma unroll
    for (int rr = 0; rr < RPT; ++rr) {
        int row = rowb * ROWS + r0 + rr * RT;
        if (row >= N) continue;
        *reinterpret_cast<float4*>(tmp + (size_t)row * FO + colb * COLS + c0) =
            make_float4(acc[rr][0], acc[rr][1], acc[rr][2], acc[rr][3]);
    }
}

// ---------- gather-side aggregation, 8 independent chains per node ----------
// One node per wave (FO=32: 2 nodes/wave). Lane covers FPL floats of the row.
// Edge loop processes 8 edges per iteration, branch-free via clamp+zero-mask;
// all 8 (csr_src -> dinv -> row) chains independent -> 8 outstanding gathers.
template<int FO, bool RELU, bool FINAL>
__global__ __launch_bounds__(256) void agg_kernel(
    const int* __restrict__ rowptr, const int* __restrict__ csr_src,
    const float* __restrict__ dinv, const float* __restrict__ tmp,
    const float* __restrict__ b, float* __restrict__ h,
    const float* __restrict__ Wl, const float* __restrict__ bl,
    float* __restrict__ out, int N)
{
    constexpr int GPW = (FO == 32) ? 2 : 1;   // node-groups per wave
    constexpr int GL  = 64 / GPW;             // lanes per group (64 or 32)
    constexpr int FPL = FO / GL;              // floats per lane (2 for FO=128, else 1)
    const int wid  = (blockIdx.x * 256 + threadIdx.x) >> 6;
    const int lane = threadIdx.x & 63;
    const int g    = lane / GL;
    const int fl   = lane % GL;
    const int node = wid * GPW + g;
    if (node >= N) return;

    const float dvd = dinv[node];
    const int jb = rowptr[node], je = rowptr[node + 1];

    float acc[8][FPL];
    #pragma unroll
    for (int u = 0; u < 8; ++u)
        #pragma unroll
        for (int q = 0; q < FPL; ++q) acc[u][q] = 0.0f;

    if (jb < je) {
        for (int j = jb; j < je; j += 8) {
            int   ss[8];
            float mm[8];
            #pragma unroll
            for (int u = 0; u < 8; ++u) {
                int jj = j + u;
                bool ok = jj < je;
                ss[u] = csr_src[ok ? jj : jb];
                mm[u] = ok ? 1.0f : 0.0f;
            }
            float ww[8];
            #pragma unroll
            for (int u = 0; u < 8; ++u) ww[u] = dinv[ss[u]] * dvd * mm[u];
            #pragma unroll
            for (int u = 0; u < 8; ++u) {
                const float* p = tmp + (size_t)ss[u] * FO + fl * FPL;
                if (FPL == 2) {
                    float2 v = *reinterpret_cast<const float2*>(p);
                    acc[u][0] += v.x * ww[u];
                    acc[u][FPL - 1] += v.y * ww[u];
                } else {
                    acc[u][0] += p[0] * ww[u];
                }
            }
        }
    }

    float a[FPL];
    #pragma unroll
    for (int q = 0; q < FPL; ++q)
        a[q] = ((acc[0][q] + acc[1][q]) + (acc[2][q] + acc[3][q]))
             + ((acc[4][q] + acc[5][q]) + (acc[6][q] + acc[7][q]));

    // self-loop
    const float d2 = dvd * dvd;
    const float* ps = tmp + (size_t)node * FO + fl * FPL;
    #pragma unroll
    for (int q = 0; q < FPL; ++q) a[q] += ps[q] * d2;

    if (FINAL) {
        float v = fmaxf(a[0] + b[fl], 0.0f);
        float r = v * Wl[fl];
        #pragma unroll
        for (int offd = 16; offd > 0; offd >>= 1)
            r += __shfl_down(r, offd, 32);
        if (fl == 0) out[node] = r + bl[0];
    } else {
        float* o = h + (size_t)node * FO + fl * FPL;
        #pragma unroll
        for (int q = 0; q < FPL; ++q) {
            float v = a[q] + b[fl * FPL + q];
            o[q] = RELU ? fmaxf(v, 0.0f) : v;
        }
    }
}

extern "C" void kernel_launch(void* const* d_in, const int* in_sizes, int n_in,
                              void* d_out, int out_size, void* d_ws, size_t ws_size,
                              hipStream_t stream)
{
    const float* x  = (const float*)d_in[0];
    const int*   ei = (const int*)d_in[1];   // int inputs arrive as int32
    const float* W1 = (const float*)d_in[2];
    const float* b1 = (const float*)d_in[3];
    const float* W2 = (const float*)d_in[4];
    const float* b2 = (const float*)d_in[5];
    const float* W3 = (const float*)d_in[6];
    const float* b3 = (const float*)d_in[7];
    const float* Wl = (const float*)d_in[8];
    const float* bl = (const float*)d_in[9];
    float* out = (float*)d_out;

    const int N = in_sizes[0] / 128;
    const int E = in_sizes[1] / 2;

    const int* src = ei;        // edge_index row 0
    const int* dst = ei + E;    // edge_index row 1

    char* ws = (char*)d_ws;
    size_t off = 0;
    auto wsalloc = [&](size_t bytes) -> void* {
        void* p = ws + off;
        off = (off + bytes + 255) & ~(size_t)255;
        return p;
    };
    const int NB = CDIV(N, 1024);
    int*   deg     = (int*)  wsalloc((size_t)N * 4);
    float* dinv    = (float*)wsalloc((size_t)N * 4);
    int*   rowptr  = (int*)  wsalloc((size_t)(N + 1) * 4);
    int*   cursor  = (int*)  wsalloc((size_t)N * 4);
    int*   bsums   = (int*)  wsalloc((size_t)NB * 4);
    int*   csr_src = (int*)  wsalloc((size_t)E * 4);
    float* B1      = (float*)wsalloc((size_t)N * 128 * 4);  // tmp
    float* B2      = (float*)wsalloc((size_t)N * 128 * 4);  // h
    // total ws use: ~55 MB

    // ---- CSR build ----
    hipMemsetAsync(deg, 0, (size_t)N * 4, stream);
    deg_kernel<<<CDIV(E, 256), 256, 0, stream>>>(dst, E, deg);
    block_scan_kernel<<<NB, 1024, 0, stream>>>(deg, rowptr, bsums, dinv, N);
    scan_bsums_kernel<<<1, 1024, 0, stream>>>(bsums, NB);
    add_offsets_kernel<<<CDIV(N + 1, 256), 256, 0, stream>>>(rowptr, cursor, bsums, N, E);
    csr_build_kernel<<<CDIV(E, 256), 256, 0, stream>>>(src, dst, cursor, csr_src, E);

    // ---- layer 1: 128 -> 128 (col-split x2) ----
    gemm_kernel<128, 128, 64, 64><<<2 * CDIV(N, 64), 256, 0, stream>>>(x, W1, B1, N);
    agg_kernel<128, true, false><<<CDIV(N, 4), 256, 0, stream>>>(
        rowptr, csr_src, dinv, B1, b1, B2, nullptr, nullptr, nullptr, N);

    // ---- layer 2: 128 -> 64 ----
    gemm_kernel<128, 64, 64, 64><<<CDIV(N, 64), 256, 0, stream>>>(B2, W2, B1, N);
    agg_kernel<64, true, false><<<CDIV(N, 4), 256, 0, stream>>>(
        rowptr, csr_src, dinv, B1, b2, B2, nullptr, nullptr, nullptr, N);

    // ---- layer 3: 64 -> 32, final linear fused into agg ----
    gemm_kernel<64, 32, 32, 64><<<CDIV(N, 64), 256, 0, stream>>>(B2, W3, B1, N);
    agg_kernel<32, true, true><<<CDIV(N, 8), 256, 0, stream>>>(
        rowptr, csr_src, dinv, B1, b3, nullptr, Wl, bl, out, N);
}

// Round 12
// 277.081 us; speedup vs baseline: 1.3252x; 1.0166x over previous
//
#include <hip/hip_runtime.h>
#include <math.h>

#define CDIV(a,b) (((a)+(b)-1)/(b))

// ---------- deg[dst]++ (int histogram), int4-vectorized ----------
__global__ __launch_bounds__(256) void deg_kernel(
    const int* __restrict__ dst, int E, int* __restrict__ deg)
{
    int e4 = blockIdx.x * 256 + threadIdx.x;
    int e  = e4 * 4;
    if (e + 4 <= E) {
        int4 d = *reinterpret_cast<const int4*>(dst + e);
        atomicAdd(&deg[d.x], 1);
        atomicAdd(&deg[d.y], 1);
        atomicAdd(&deg[d.z], 1);
        atomicAdd(&deg[d.w], 1);
    } else {
        for (; e < E; ++e) atomicAdd(&deg[dst[e]], 1);
    }
}

// ---------- hierarchical exclusive scan (pass 1 also emits dinv) ----------
__global__ __launch_bounds__(1024) void block_scan_kernel(
    const int* __restrict__ deg, int* __restrict__ excl,
    int* __restrict__ bsums, float* __restrict__ dinv, int N)
{
    __shared__ int buf[1024];
    const int t = threadIdx.x;
    const int i = blockIdx.x * 1024 + t;
    int v = (i < N) ? deg[i] : 0;
    buf[t] = v;
    __syncthreads();
    for (int offs = 1; offs < 1024; offs <<= 1) {
        int add = (t >= offs) ? buf[t - offs] : 0;
        __syncthreads();
        buf[t] += add;
        __syncthreads();
    }
    if (i < N) {
        excl[i] = buf[t] - v;
        dinv[i] = 1.0f / sqrtf((float)v + 1.0f);  // +1 self-loop
    }
    if (t == 1023) bsums[blockIdx.x] = buf[t];
}

__global__ __launch_bounds__(1024) void scan_bsums_kernel(
    int* __restrict__ bsums, int nb)
{
    __shared__ int buf[1024];
    const int t = threadIdx.x;
    int v = (t < nb) ? bsums[t] : 0;
    buf[t] = v;
    __syncthreads();
    for (int offs = 1; offs < 1024; offs <<= 1) {
        int add = (t >= offs) ? buf[t - offs] : 0;
        __syncthreads();
        buf[t] += add;
        __syncthreads();
    }
    if (t < nb) bsums[t] = buf[t] - v;  // exclusive
}

__global__ __launch_bounds__(256) void add_offsets_kernel(
    int* __restrict__ rowptr, int* __restrict__ cursor,
    const int* __restrict__ bsums, int N, int E)
{
    int i = blockIdx.x * 256 + threadIdx.x;
    if (i < N) {
        int v = rowptr[i] + bsums[i >> 10];
        rowptr[i] = v;
        cursor[i] = v;
    }
    if (i == N) rowptr[N] = E;
}

// ---------- scatter edges into CSR slots ----------
__global__ __launch_bounds__(256) void csr_build_kernel(
    const int* __restrict__ src, const int* __restrict__ dst,
    int* __restrict__ cursor, int* __restrict__ csr_src, int E)
{
    int e = blockIdx.x * 256 + threadIdx.x;
    if (e >= E) return;
    int pos = atomicAdd(&cursor[dst[e]], 1);
    csr_src[pos] = src[e];
}

// ---------- GEMM: tmp = A@W ----------
// W (col-slice) staged in LDS once, single barrier, barrier-free k-loop.
// A read from global: CT lanes of a row-group hit the same float4 (broadcast).
template<int FI, int FO, int COLS, int ROWS>
__global__ __launch_bounds__(256, 4) void gemm_kernel(
    const float* __restrict__ A, const float* __restrict__ W,
    float* __restrict__ tmp, int N)
{
    constexpr int NCB = FO / COLS;    // col-blocks
    constexpr int CT  = COLS / 4;     // col-threads (float4 each)
    constexpr int RT  = 256 / CT;     // row-threads
    constexpr int RPT = ROWS / RT;    // rows per thread

    __shared__ float sW[FI][COLS];

    const int t    = threadIdx.x;
    const int colb = (NCB > 1) ? (blockIdx.x % NCB) : 0;
    const int rowb = (NCB > 1) ? (blockIdx.x / NCB) : blockIdx.x;

    #pragma unroll
    for (int it = 0; it < (FI * COLS / 4) / 256; ++it) {
        int idx = it * 256 + t;
        int k   = idx / CT;
        int cq  = idx % CT;
        *reinterpret_cast<float4*>(&sW[k][cq * 4]) =
            *reinterpret_cast<const float4*>(W + (size_t)k * FO + colb * COLS + cq * 4);
    }
    __syncthreads();

    const int c0 = (t % CT) * 4;
    const int r0 = t / CT;

    const float* aptr[RPT];
    #pragma unroll
    for (int rr = 0; rr < RPT; ++rr) {
        int row = rowb * ROWS + r0 + rr * RT;
        int rc  = (row < N) ? row : (N - 1);   // clamp loads, guard stores
        aptr[rr] = A + (size_t)rc * FI;
    }

    float acc[RPT][4];
    #pragma unroll
    for (int rr = 0; rr < RPT; ++rr)
        #pragma unroll
        for (int c = 0; c < 4; ++c) acc[rr][c] = 0.0f;

    #pragma unroll 8
    for (int k4 = 0; k4 < FI / 4; ++k4) {
        float4 w0 = *reinterpret_cast<const float4*>(&sW[k4 * 4 + 0][c0]);
        float4 w1 = *reinterpret_cast<const float4*>(&sW[k4 * 4 + 1][c0]);
        float4 w2 = *reinterpret_cast<const float4*>(&sW[k4 * 4 + 2][c0]);
        float4 w3 = *reinterpret_cast<const float4*>(&sW[k4 * 4 + 3][c0]);
        #pragma unroll
        for (int rr = 0; rr < RPT; ++rr) {
            float4 a = *reinterpret_cast<const float4*>(aptr[rr] + k4 * 4);
            acc[rr][0] += a.x * w0.x + a.y * w1.x + a.z * w2.x + a.w * w3.x;
            acc[rr][1] += a.x * w0.y + a.y * w1.y + a.z * w2.y + a.w * w3.y;
            acc[rr][2] += a.x * w0.z + a.y * w1.z + a.z * w2.z + a.w * w3.z;
            acc[rr][3] += a.x * w0.w + a.y * w1.w + a.z * w2.w + a.w * w3.w;
        }
    }

    #pragma unroll
    for (int rr = 0; rr < RPT; ++rr) {
        int row = rowb * ROWS + r0 + rr * RT;
        if (row >= N) continue;
        *reinterpret_cast<float4*>(tmp + (size_t)row * FO + colb * COLS + c0) =
            make_float4(acc[rr][0], acc[rr][1], acc[rr][2], acc[rr][3]);
    }
}

// ---------- gather-side aggregation, float2 lanes, 8 chains ----------
// GL lanes cover one node's FO-row as float2 (FPL=2). GPW=64/GL nodes per
// wave. Edge loop does 8 edges/iter, branch-free clamp+zero-mask, 8
// independent (csr_src -> dinv -> row) chains. FINAL fuses relu+Wl dot +
// 16-lane shuffle reduce + bl.
template<int FO, bool RELU, bool FINAL>
__global__ __launch_bounds__(256) void agg_kernel(
    const int* __restrict__ rowptr, const int* __restrict__ csr_src,
    const float* __restrict__ dinv, const float* __restrict__ tmp,
    const float* __restrict__ b, float* __restrict__ h,
    const float* __restrict__ Wl, const float* __restrict__ bl,
    float* __restrict__ out, int N)
{
    constexpr int GL  = (FO == 128) ? 64 : (FO == 64 ? 32 : 16);
    constexpr int GPW = 64 / GL;
    const int wid  = (blockIdx.x * 256 + threadIdx.x) >> 6;
    const int lane = threadIdx.x & 63;
    const int g    = lane / GL;
    const int fl   = lane % GL;
    const int node = wid * GPW + g;
    if (node >= N) return;

    const float dvd = dinv[node];
    const int jb = rowptr[node], je = rowptr[node + 1];

    float2 acc[8];
    #pragma unroll
    for (int u = 0; u < 8; ++u) { acc[u].x = 0.f; acc[u].y = 0.f; }

    if (jb < je) {
        for (int j = jb; j < je; j += 8) {
            int   ss[8];
            float mm[8];
            #pragma unroll
            for (int u = 0; u < 8; ++u) {
                int jj = j + u;
                bool ok = jj < je;
                ss[u] = csr_src[ok ? jj : jb];
                mm[u] = ok ? 1.0f : 0.0f;
            }
            float ww[8];
            #pragma unroll
            for (int u = 0; u < 8; ++u) ww[u] = dinv[ss[u]] * dvd * mm[u];
            #pragma unroll
            for (int u = 0; u < 8; ++u) {
                float2 v = *reinterpret_cast<const float2*>(
                    tmp + (size_t)ss[u] * FO + fl * 2);
                acc[u].x += v.x * ww[u];
                acc[u].y += v.y * ww[u];
            }
        }
    }

    float ax = ((acc[0].x + acc[1].x) + (acc[2].x + acc[3].x))
             + ((acc[4].x + acc[5].x) + (acc[6].x + acc[7].x));
    float ay = ((acc[0].y + acc[1].y) + (acc[2].y + acc[3].y))
             + ((acc[4].y + acc[5].y) + (acc[6].y + acc[7].y));

    // self-loop
    const float d2 = dvd * dvd;
    float2 sv = *reinterpret_cast<const float2*>(tmp + (size_t)node * FO + fl * 2);
    ax += sv.x * d2;
    ay += sv.y * d2;

    const float2 bb = *reinterpret_cast<const float2*>(b + fl * 2);
    if (FINAL) {
        float vx = fmaxf(ax + bb.x, 0.0f);
        float vy = fmaxf(ay + bb.y, 0.0f);
        const float2 wl = *reinterpret_cast<const float2*>(Wl + fl * 2);
        float r = vx * wl.x + vy * wl.y;
        r += __shfl_down(r, 8, 16);
        r += __shfl_down(r, 4, 16);
        r += __shfl_down(r, 2, 16);
        r += __shfl_down(r, 1, 16);
        if (fl == 0) out[node] = r + bl[0];
    } else {
        float2 o;
        o.x = RELU ? fmaxf(ax + bb.x, 0.0f) : (ax + bb.x);
        o.y = RELU ? fmaxf(ay + bb.y, 0.0f) : (ay + bb.y);
        *reinterpret_cast<float2*>(h + (size_t)node * FO + fl * 2) = o;
    }
}

extern "C" void kernel_launch(void* const* d_in, const int* in_sizes, int n_in,
                              void* d_out, int out_size, void* d_ws, size_t ws_size,
                              hipStream_t stream)
{
    const float* x  = (const float*)d_in[0];
    const int*   ei = (const int*)d_in[1];   // int inputs arrive as int32
    const float* W1 = (const float*)d_in[2];
    const float* b1 = (const float*)d_in[3];
    const float* W2 = (const float*)d_in[4];
    const float* b2 = (const float*)d_in[5];
    const float* W3 = (const float*)d_in[6];
    const float* b3 = (const float*)d_in[7];
    const float* Wl = (const float*)d_in[8];
    const float* bl = (const float*)d_in[9];
    float* out = (float*)d_out;

    const int N = in_sizes[0] / 128;
    const int E = in_sizes[1] / 2;

    const int* src = ei;        // edge_index row 0
    const int* dst = ei + E;    // edge_index row 1

    char* ws = (char*)d_ws;
    size_t off = 0;
    auto wsalloc = [&](size_t bytes) -> void* {
        void* p = ws + off;
        off = (off + bytes + 255) & ~(size_t)255;
        return p;
    };
    const int NB = CDIV(N, 1024);
    int*   deg     = (int*)  wsalloc((size_t)N * 4);
    float* dinv    = (float*)wsalloc((size_t)N * 4);
    int*   rowptr  = (int*)  wsalloc((size_t)(N + 1) * 4);
    int*   cursor  = (int*)  wsalloc((size_t)N * 4);
    int*   bsums   = (int*)  wsalloc((size_t)NB * 4);
    int*   csr_src = (int*)  wsalloc((size_t)E * 4);
    float* B1      = (float*)wsalloc((size_t)N * 128 * 4);  // tmp
    float* B2      = (float*)wsalloc((size_t)N * 128 * 4);  // h
    // total ws use: ~55 MB

    // ---- CSR build ----
    hipMemsetAsync(deg, 0, (size_t)N * 4, stream);
    deg_kernel<<<CDIV(CDIV(E, 4), 256), 256, 0, stream>>>(dst, E, deg);
    block_scan_kernel<<<NB, 1024, 0, stream>>>(deg, rowptr, bsums, dinv, N);
    scan_bsums_kernel<<<1, 1024, 0, stream>>>(bsums, NB);
    add_offsets_kernel<<<CDIV(N + 1, 256), 256, 0, stream>>>(rowptr, cursor, bsums, N, E);
    csr_build_kernel<<<CDIV(E, 256), 256, 0, stream>>>(src, dst, cursor, csr_src, E);

    // ---- layer 1: 128 -> 128 (col-split x2) ----
    gemm_kernel<128, 128, 64, 64><<<2 * CDIV(N, 64), 256, 0, stream>>>(x, W1, B1, N);
    agg_kernel<128, true, false><<<CDIV(N, 4), 256, 0, stream>>>(
        rowptr, csr_src, dinv, B1, b1, B2, nullptr, nullptr, nullptr, N);

    // ---- layer 2: 128 -> 64 (2 nodes/wave) ----
    gemm_kernel<128, 64, 64, 64><<<CDIV(N, 64), 256, 0, stream>>>(B2, W2, B1, N);
    agg_kernel<64, true, false><<<CDIV(N, 8), 256, 0, stream>>>(
        rowptr, csr_src, dinv, B1, b2, B2, nullptr, nullptr, nullptr, N);

    // ---- layer 3: 64 -> 32, final linear fused (4 nodes/wave) ----
    gemm_kernel<64, 32, 32, 64><<<CDIV(N, 64), 256, 0, stream>>>(B2, W3, B1, N);
    agg_kernel<32, true, true><<<CDIV(N, 16), 256, 0, stream>>>(
        rowptr, csr_src, dinv, B1, b3, nullptr, Wl, bl, out, N);
}